// Round 4
// baseline (57.359 us; speedup 1.0000x reference)
//
#include <hip/hip_runtime.h>
#include <math.h>

#define N_UNITS_C 524288
#define BATCH_C 16384
#define SPW 4   // segments per wave

typedef float f32x4 __attribute__((ext_vector_type(4)));
typedef f32x4 __attribute__((aligned(4))) f32x4_u;   // 4-byte-aligned vector load

struct F9 { f32x4 a; f32x4 b; float c; };
__device__ inline F9 load9(const float* __restrict__ p) {
    F9 r;
    r.a = *reinterpret_cast<const f32x4_u*>(p);
    r.b = *reinterpret_cast<const f32x4_u*>(p + 4);
    r.c = p[8];
    return r;
}
__device__ inline F9 lds_load9(const float* p) {
    F9 r;
    r.a = *reinterpret_cast<const f32x4*>(p);
    r.b = *reinterpret_cast<const f32x4*>(p + 4);
    r.c = p[8];
    return r;
}

// ---------------------------------------------------------------------------
// Kernel 1: segment boundary detection for BOTH sides (grid.y = side).
// start[b] = first index i with seg[i] >= b; start[BATCH]=n.
// ---------------------------------------------------------------------------
__global__ __launch_bounds__(256) void seg_starts_kernel(
    const int* __restrict__ lseg, const int* __restrict__ rseg, int n,
    int* __restrict__ lstart, int* __restrict__ rstart)
{
    const int* __restrict__ seg = blockIdx.y ? rseg : lseg;
    int* __restrict__ start = blockIdx.y ? rstart : lstart;
    int i = blockIdx.x * blockDim.x + threadIdx.x;
    if (i >= n) return;
    int s = seg[i];
    int prev = (i == 0) ? -1 : seg[i - 1];
    for (int b = prev + 1; b <= s; ++b) start[b] = i;
    if (i == n - 1) {
        for (int b = s + 1; b <= BATCH_C; ++b) start[b] = n;
    }
}

// ---------------------------------------------------------------------------
// Kernel 2: fused per-unit MLP (9 -> 64, ReLU) + ragged segment sum.
// Lane = channel. 4 segments (~128 units) per wave, streamed through
// double-buffered 64-unit LDS windows (global loads reg-prefetched one
// window ahead). Inner compute is a 2-deep ping-pong software pipeline:
// ds_reads for unit i+2/i+3 issue before unit i's FMAs retire, so the
// per-unit lgkmcnt(0) stall of R3 disappears. Flush at segment boundary =
// single store per lane (exactly-once -> deterministic).
// ---------------------------------------------------------------------------
__global__ __launch_bounds__(256, 4) void pool_kernel(
    const float* __restrict__ lfeats, const float* __restrict__ rfeats,
    const int* __restrict__ lstart, const int* __restrict__ rstart,
    const float* __restrict__ W1, const float* __restrict__ b1,
    float* __restrict__ pooled, int nunits)
{
    const int lane = threadIdx.x & 63;
    const int wv   = threadIdx.x >> 6;
    const int side = blockIdx.y;
    const int S0   = (blockIdx.x * 4 + wv) * SPW;

    // 66 slots x 12 floats: slots 64,65 absorb the pipeline's overshoot reads
    __shared__ float lds[4][2][66 * 12];

    const float* __restrict__ feats = side ? rfeats : lfeats;
    const int*   __restrict__ start = side ? rstart : lstart;

    // lane owns channel `lane`: W1[:, lane] + b1[lane]
    float w0 = W1[0 * 64 + lane], w1 = W1[1 * 64 + lane], w2 = W1[2 * 64 + lane];
    float w3 = W1[3 * 64 + lane], w4 = W1[4 * 64 + lane], w5 = W1[5 * 64 + lane];
    float w6 = W1[6 * 64 + lane], w7 = W1[7 * 64 + lane], w8 = W1[8 * 64 + lane];
    const float bias = b1[lane];

    // lane l (l<=SPW) holds start[S0+l]; broadcast via shfl
    int sv = start[S0 + (lane < SPW + 1 ? lane : SPW)];
    const int s_abs   = __shfl(sv, 0, 64);
    const int end_abs = __shfl(sv, SPW, 64);

    int c   = 0;                   // local segment cursor
    int e_c = __shfl(sv, 1, 64);   // absolute end of segment c

    float acc = 0.0f;
    int bufsel = 0;
    int base = s_abs;

#define UNIT(F)  do {                                   \
        float h1 = bias, h2 = (F).c * w8;               \
        h1 = fmaf((F).a.x, w0, h1);                     \
        h2 = fmaf((F).b.x, w4, h2);                     \
        h1 = fmaf((F).a.y, w1, h1);                     \
        h2 = fmaf((F).b.y, w5, h2);                     \
        h1 = fmaf((F).a.z, w2, h1);                     \
        h2 = fmaf((F).b.z, w6, h2);                     \
        h1 = fmaf((F).a.w, w3, h1);                     \
        h2 = fmaf((F).b.w, w7, h2);                     \
        acc += fmaxf(h1 + h2, 0.0f);                    \
    } while (0)

    F9 pre;
    if (base < end_abs) {
        int u = base + lane; if (u > nunits - 1) u = nunits - 1;
        pre = load9(feats + (size_t)u * 9);
    }

    while (base < end_abs) {
        float* __restrict__ bp = &lds[wv][bufsel][0];
        float* sp = bp + lane * 12;
        *reinterpret_cast<f32x4*>(sp)     = pre.a;   // ds_write_b128
        *reinterpret_cast<f32x4*>(sp + 4) = pre.b;
        sp[8] = pre.c;

        int nbase = base + 64;
        if (nbase < end_abs) {   // prefetch next window during this one's compute
            int u = nbase + lane; if (u > nunits - 1) u = nunits - 1;
            pre = load9(feats + (size_t)u * 9);
        }

        // drain ds_writes before cross-lane reads; block compiler reordering
        asm volatile("s_waitcnt lgkmcnt(0)" ::: "memory");

        int wend = end_abs - base; if (wend > 64) wend = 64;
        int ul = 0;
        while (true) {
            const int ecl = e_c - base;            // may exceed wend
            const int hi = ecl < wend ? ecl : wend;
            if (hi > ul) {
                // 2-deep ping-pong software pipeline over chunk [ul, hi)
                const float* pA = bp + ul * 12;
                F9 fA = lds_load9(pA);
                F9 fB = lds_load9(pA + 12);
                int i = ul;
                for (; i + 2 <= hi; i += 2) {
                    UNIT(fA);
                    fA = lds_load9(bp + (i + 2) * 12);
                    UNIT(fB);
                    fB = lds_load9(bp + (i + 3) * 12);
                }
                if (i < hi) UNIT(fA);
            }
            ul = hi;
            if (ecl <= wend) {   // segment c complete (possibly empty) -> flush
                pooled[(size_t)(S0 + c) * 128 + side * 64 + lane] = acc;
                acc = 0.0f;
                ++c;
                if (c >= SPW) break;
                e_c = __shfl(sv, c + 1, 64);
            } else break;        // segment continues into next window
        }
        base = nbase;
        bufsel ^= 1;
    }
    // trailing empty segments (or fully-empty wave)
    while (c < SPW) {
        pooled[(size_t)(S0 + c) * 128 + side * 64 + lane] = 0.0f;
        ++c;
    }
#undef UNIT
}

// ---------------------------------------------------------------------------
// Kernel 3: head MLP. combined[B,128] @ Wc1[128,32] + bc1 -> relu
//           -> @ Wc2[32,1] + bc2 -> sigmoid.
// ---------------------------------------------------------------------------
__global__ __launch_bounds__(256) void head_kernel(
    const float* __restrict__ pooled, const float* __restrict__ Wc1,
    const float* __restrict__ bc1, const float* __restrict__ Wc2,
    const float* __restrict__ bc2, float* __restrict__ out)
{
    __shared__ float sW[128 * 32];
    __shared__ float sb[32];
    __shared__ float sw2[32];

    for (int t = threadIdx.x; t < 128 * 32; t += 256) sW[t] = Wc1[t];
    if (threadIdx.x < 32) {
        sb[threadIdx.x] = bc1[threadIdx.x];
        sw2[threadIdx.x] = Wc2[threadIdx.x];
    }
    __syncthreads();

    const int lane = threadIdx.x & 63;
    const int wave = threadIdx.x >> 6;
    const int half = lane >> 5;
    const int j = lane & 31;

    const int row = blockIdx.x * 8 + wave * 2 + half;
    const float* __restrict__ p = pooled + (size_t)row * 128;

    float acc = sb[j];
#pragma unroll 16
    for (int k = 0; k < 128; ++k) acc = fmaf(p[k], sW[k * 32 + j], acc);

    float h = fmaxf(acc, 0.0f) * sw2[j];
#pragma unroll
    for (int off = 16; off > 0; off >>= 1) h += __shfl_xor(h, off, 64);

    if (j == 0) {
        float logit = h + bc2[0];
        out[row] = 1.0f / (1.0f + expf(-logit));
    }
}

// ---------------------------------------------------------------------------
extern "C" void kernel_launch(void* const* d_in, const int* in_sizes, int n_in,
                              void* d_out, int out_size, void* d_ws, size_t ws_size,
                              hipStream_t stream)
{
    const float* lfeats = (const float*)d_in[0];
    const float* rfeats = (const float*)d_in[1];
    const int*   lseg   = (const int*)d_in[2];
    const int*   rseg   = (const int*)d_in[3];
    const float* W1     = (const float*)d_in[4];
    const float* b1     = (const float*)d_in[5];
    const float* Wc1    = (const float*)d_in[6];
    const float* bc1    = (const float*)d_in[7];
    const float* Wc2    = (const float*)d_in[8];
    const float* bc2    = (const float*)d_in[9];
    float* out = (float*)d_out;

    const int n = in_sizes[2];  // N_UNITS per side

    float* pooled = (float*)d_ws;
    int* lstart = (int*)((char*)d_ws + (size_t)BATCH_C * 128 * sizeof(float));
    int* rstart = lstart + (BATCH_C + 16);

    seg_starts_kernel<<<dim3((n + 255) / 256, 2), 256, 0, stream>>>(
        lseg, rseg, n, lstart, rstart);

    pool_kernel<<<dim3(BATCH_C / (SPW * 4), 2), 256, 0, stream>>>(
        lfeats, rfeats, lstart, rstart, W1, b1, pooled, n);

    head_kernel<<<BATCH_C / 8, 256, 0, stream>>>(pooled, Wc1, bc1, Wc2, bc2, out);
}

// Round 5
// 48.269 us; speedup vs baseline: 1.1883x; 1.1883x over previous
//
#include <hip/hip_runtime.h>
#include <math.h>

#define BATCH_C 16384
#define SPW 4   // segments per wave

typedef float f32x4 __attribute__((ext_vector_type(4)));
typedef f32x4 __attribute__((aligned(4))) f32x4_u;   // dword-aligned vector load

struct F9 { f32x4 a; f32x4 b; float c; };
__device__ inline F9 load9g(const float* __restrict__ p) {   // global, 4B-aligned
    F9 r;
    r.a = *reinterpret_cast<const f32x4_u*>(p);
    r.b = *reinterpret_cast<const f32x4_u*>(p + 4);
    r.c = p[8];
    return r;
}
__device__ inline F9 load9l(const float* p) {                // LDS, 16B-aligned
    F9 r;
    r.a = *reinterpret_cast<const f32x4*>(p);
    r.b = *reinterpret_cast<const f32x4*>(p + 4);
    r.c = p[8];
    return r;
}

// ---------------------------------------------------------------------------
// Kernel 1: segment boundary detection for BOTH sides (grid.y = side).
// ---------------------------------------------------------------------------
__global__ __launch_bounds__(256) void seg_starts_kernel(
    const int* __restrict__ lseg, const int* __restrict__ rseg, int n,
    int* __restrict__ lstart, int* __restrict__ rstart)
{
    const int* __restrict__ seg = blockIdx.y ? rseg : lseg;
    int* __restrict__ start = blockIdx.y ? rstart : lstart;
    int i = blockIdx.x * blockDim.x + threadIdx.x;
    if (i >= n) return;
    int s = seg[i];
    int prev = (i == 0) ? -1 : seg[i - 1];
    for (int b = prev + 1; b <= s; ++b) start[b] = i;
    if (i == n - 1) {
        for (int b = s + 1; b <= BATCH_C; ++b) start[b] = n;
    }
}

// ---------------------------------------------------------------------------
// Kernel 2: fused per-unit MLP (9->64, ReLU) + ragged segment sum.
// 4 groups x 16 lanes per wave. Group g processes unit p+g of each pass;
// lane (g, j) computes channels j*4..j*4+3 (36 weight VGPRs). DS reads per
// pass = 3 instrs with 4 distinct addresses (16-way broadcast = free), so
// DS-pipe cost/unit is ~4x lower than the wave-uniform scheme of R3/R4.
// Per-segment windows tile the wave's contiguous unit range; global loads
// are reg-prefetched one window ahead. Interior passes unmasked; single
// masked tail pass per window. Flush: shfl_xor(16,32) + float4 store.
// ---------------------------------------------------------------------------
__global__ __launch_bounds__(256, 4) void pool_kernel(
    const float* __restrict__ lfeats, const float* __restrict__ rfeats,
    const int* __restrict__ lstart, const int* __restrict__ rstart,
    const float* __restrict__ W1, const float* __restrict__ b1,
    float* __restrict__ pooled, int nunits)
{
    const int lane = threadIdx.x & 63;
    const int wv   = threadIdx.x >> 6;
    const int side = blockIdx.y;
    const int S0   = (blockIdx.x * 4 + wv) * SPW;
    const int g    = lane >> 4;    // group = unit-within-pass
    const int j    = lane & 15;    // channel quad: channels j*4 .. j*4+3

    __shared__ float lds[4][72 * 12];   // 72 slots: 8 pad slots absorb pipeline overshoot
    float* __restrict__ bp = &lds[wv][0];

    const float* __restrict__ feats = side ? rfeats : lfeats;
    const int*   __restrict__ start = side ? rstart : lstart;

    // weights: wc[t][k] = W1[k][j*4+t], biasv[t] = b1[j*4+t]  (40 VGPRs)
    float wc[4][9], biasv[4];
#pragma unroll
    for (int t = 0; t < 4; ++t) {
        const int ch = j * 4 + t;
        biasv[t] = b1[ch];
#pragma unroll
        for (int k = 0; k < 9; ++k) wc[t][k] = W1[k * 64 + ch];
    }

    int sv = start[S0 + (lane <= SPW ? lane : SPW)];
    const int s_abs   = __shfl(sv, 0, 64);
    const int end_abs = __shfl(sv, SPW, 64);

#define CH(F, WT, BT, ACC) do {                         \
        float h1 = fmaf((F).a.x, WT[0], BT);            \
        float h2 = (F).c * WT[8];                       \
        h1 = fmaf((F).a.y, WT[1], h1);                  \
        h2 = fmaf((F).b.x, WT[4], h2);                  \
        h1 = fmaf((F).a.z, WT[2], h1);                  \
        h2 = fmaf((F).b.y, WT[5], h2);                  \
        h1 = fmaf((F).a.w, WT[3], h1);                  \
        h2 = fmaf((F).b.z, WT[6], h2);                  \
        h2 = fmaf((F).b.w, WT[7], h2);                  \
        ACC += fmaxf(h1 + h2, 0.0f);                    \
    } while (0)
#define CHM(F, WT, BT, ACC, V) do {                     \
        float h1 = fmaf((F).a.x, WT[0], BT);            \
        float h2 = (F).c * WT[8];                       \
        h1 = fmaf((F).a.y, WT[1], h1);                  \
        h2 = fmaf((F).b.x, WT[4], h2);                  \
        h1 = fmaf((F).a.z, WT[2], h1);                  \
        h2 = fmaf((F).b.y, WT[5], h2);                  \
        h1 = fmaf((F).a.w, WT[3], h1);                  \
        h2 = fmaf((F).b.z, WT[6], h2);                  \
        h2 = fmaf((F).b.w, WT[7], h2);                  \
        ACC += (V) ? fmaxf(h1 + h2, 0.0f) : 0.0f;       \
    } while (0)
#define PASS_NM(F) do {                                 \
        CH(F, wc[0], biasv[0], a0);                     \
        CH(F, wc[1], biasv[1], a1);                     \
        CH(F, wc[2], biasv[2], a2);                     \
        CH(F, wc[3], biasv[3], a3);                     \
    } while (0)
#define PASS_M(F, V) do {                               \
        CHM(F, wc[0], biasv[0], a0, V);                 \
        CHM(F, wc[1], biasv[1], a1, V);                 \
        CHM(F, wc[2], biasv[2], a2, V);                 \
        CHM(F, wc[3], biasv[3], a3, V);                 \
    } while (0)

    F9 pre;
    if (s_abs < end_abs) {
        int u = s_abs + lane; if (u > nunits - 1) u = nunits - 1;
        pre = load9g(feats + (size_t)u * 9);
    }

    for (int c = 0; c < SPW; ++c) {
        const int sc = __shfl(sv, c, 64);
        const int ec = __shfl(sv, c + 1, 64);
        float a0 = 0.f, a1 = 0.f, a2 = 0.f, a3 = 0.f;

        for (int base = sc; base < ec; base += 64) {
            const int cnt = (ec - base < 64) ? (ec - base) : 64;

            // stage current window (prefetched in `pre`)
            float* sp = bp + lane * 12;
            *reinterpret_cast<f32x4*>(sp)     = pre.a;
            *reinterpret_cast<f32x4*>(sp + 4) = pre.b;
            sp[8] = pre.c;

            // prefetch next window (windows tile the contiguous range)
            const int nxt = (base + 64 < ec) ? (base + 64) : ec;
            if (nxt < end_abs) {
                int u = nxt + lane; if (u > nunits - 1) u = nunits - 1;
                pre = load9g(feats + (size_t)u * 9);
            }

            // drain ds_writes before cross-lane reads (same-wave, in-order DS)
            asm volatile("s_waitcnt lgkmcnt(0)" ::: "memory");

            const float* __restrict__ gb = bp + g * 12;
            const int cnt4 = cnt & ~3;
            F9 fA = load9l(gb);
            F9 fB = load9l(gb + 48);
            int p = 0;
            for (; p + 8 <= cnt4; p += 8) {      // unmasked interior, 2-deep pipeline
                PASS_NM(fA);
                fA = load9l(gb + (p + 8) * 12);
                PASS_NM(fB);
                fB = load9l(gb + (p + 12) * 12);
            }
            if (p + 4 <= cnt4) {                  // odd full pass
                PASS_NM(fA);
                fA = fB;
                p += 4;
            }
            if (p < cnt) {                        // masked tail pass
                const bool valid = (p + g) < cnt;
                PASS_M(fA, valid);
            }
        }

        // reduce across the 4 groups (lane bits 4,5); j preserved
        a0 += __shfl_xor(a0, 16, 64); a0 += __shfl_xor(a0, 32, 64);
        a1 += __shfl_xor(a1, 16, 64); a1 += __shfl_xor(a1, 32, 64);
        a2 += __shfl_xor(a2, 16, 64); a2 += __shfl_xor(a2, 32, 64);
        a3 += __shfl_xor(a3, 16, 64); a3 += __shfl_xor(a3, 32, 64);

        if (g == 0) {
            f32x4 o; o.x = a0; o.y = a1; o.z = a2; o.w = a3;
            *reinterpret_cast<f32x4*>(
                pooled + (size_t)(S0 + c) * 128 + side * 64 + j * 4) = o;
        }
    }
#undef PASS_M
#undef PASS_NM
#undef CHM
#undef CH
}

// ---------------------------------------------------------------------------
// Kernel 3: head MLP. combined[B,128] @ Wc1[128,32] + bc1 -> relu
//           -> @ Wc2[32,1] + bc2 -> sigmoid.  (f32x4 row loads)
// ---------------------------------------------------------------------------
__global__ __launch_bounds__(256) void head_kernel(
    const float* __restrict__ pooled, const float* __restrict__ Wc1,
    const float* __restrict__ bc1, const float* __restrict__ Wc2,
    const float* __restrict__ bc2, float* __restrict__ out)
{
    __shared__ float sW[128 * 32];
    __shared__ float sb[32];
    __shared__ float sw2[32];

    for (int t = threadIdx.x; t < 128 * 32; t += 256) sW[t] = Wc1[t];
    if (threadIdx.x < 32) {
        sb[threadIdx.x] = bc1[threadIdx.x];
        sw2[threadIdx.x] = Wc2[threadIdx.x];
    }
    __syncthreads();

    const int lane = threadIdx.x & 63;
    const int wave = threadIdx.x >> 6;
    const int half = lane >> 5;
    const int j = lane & 31;

    const int row = blockIdx.x * 8 + wave * 2 + half;
    const f32x4* __restrict__ p4 =
        reinterpret_cast<const f32x4*>(pooled + (size_t)row * 128);

    float acc = sb[j];
#pragma unroll 8
    for (int k4 = 0; k4 < 32; ++k4) {
        f32x4 v = p4[k4];
        acc = fmaf(v.x, sW[(k4 * 4 + 0) * 32 + j], acc);
        acc = fmaf(v.y, sW[(k4 * 4 + 1) * 32 + j], acc);
        acc = fmaf(v.z, sW[(k4 * 4 + 2) * 32 + j], acc);
        acc = fmaf(v.w, sW[(k4 * 4 + 3) * 32 + j], acc);
    }

    float h = fmaxf(acc, 0.0f) * sw2[j];
#pragma unroll
    for (int off = 16; off > 0; off >>= 1) h += __shfl_xor(h, off, 64);

    if (j == 0) {
        float logit = h + bc2[0];
        out[row] = 1.0f / (1.0f + expf(-logit));
    }
}

// ---------------------------------------------------------------------------
extern "C" void kernel_launch(void* const* d_in, const int* in_sizes, int n_in,
                              void* d_out, int out_size, void* d_ws, size_t ws_size,
                              hipStream_t stream)
{
    const float* lfeats = (const float*)d_in[0];
    const float* rfeats = (const float*)d_in[1];
    const int*   lseg   = (const int*)d_in[2];
    const int*   rseg   = (const int*)d_in[3];
    const float* W1     = (const float*)d_in[4];
    const float* b1     = (const float*)d_in[5];
    const float* Wc1    = (const float*)d_in[6];
    const float* bc1    = (const float*)d_in[7];
    const float* Wc2    = (const float*)d_in[8];
    const float* bc2    = (const float*)d_in[9];
    float* out = (float*)d_out;

    const int n = in_sizes[2];  // N_UNITS per side

    float* pooled = (float*)d_ws;
    int* lstart = (int*)((char*)d_ws + (size_t)BATCH_C * 128 * sizeof(float));
    int* rstart = lstart + (BATCH_C + 16);

    seg_starts_kernel<<<dim3((n + 255) / 256, 2), 256, 0, stream>>>(
        lseg, rseg, n, lstart, rstart);

    pool_kernel<<<dim3(BATCH_C / (SPW * 4), 2), 256, 0, stream>>>(
        lfeats, rfeats, lstart, rstart, W1, b1, pooled, n);

    head_kernel<<<BATCH_C / 8, 256, 0, stream>>>(pooled, Wc1, bc1, Wc2, bc2, out);
}